// Round 1
// baseline (135.672 us; speedup 1.0000x reference)
//
#include <hip/hip_runtime.h>
#include <math.h>

#define D_DIM 100000
#define W_DIM 128
#define BATCH 4096
#define NOREP 0x7FFFFFFF

// ---------------------------------------------------------------------------
// Workspace layout (ws_size is ~256 MB, we need < 5 MB):
//   inv1 : int[D_DIM]            at ws + 0        (400000 B)
//   inv2 : int[D_DIM]            at ws + 400000   (400000 B)
//   p1   : float[BATCH * W_DIM]  at ws + 800000   (2097152 B)
//   p2   : float[BATCH * W_DIM]  at ws + 2897152  (2097152 B)
// inv[i] = min batch index b whose idx equals column i (the "representative"),
// or NOREP if the column is unused. Distinct columns always get distinct
// representatives, so p-buffer rows never collide.
// ---------------------------------------------------------------------------

// K1: init both inverse maps to NOREP. 2*D_DIM ints = 50000 int4 stores.
__global__ __launch_bounds__(256) void k_init(int* __restrict__ inv)
{
    const int t = blockIdx.x * 256 + threadIdx.x;
    if (t < (2 * D_DIM) / 4)
        reinterpret_cast<int4*>(inv)[t] = make_int4(NOREP, NOREP, NOREP, NOREP);
}

// K2: scatter batch index into the inverse maps (min = deterministic rep).
__global__ __launch_bounds__(256) void k_scatter(const int* __restrict__ idx1,
                                                 const int* __restrict__ idx2,
                                                 int* __restrict__ inv1,
                                                 int* __restrict__ inv2)
{
    const int b = blockIdx.x * 256 + threadIdx.x;
    if (b < BATCH) {
        atomicMin(&inv1[idx1[b]], b);
        atomicMin(&inv2[idx2[b]], b);
    }
}

// K3: inverted gather. Thread <-> column i; lanes cover adjacent columns so
// the surviving loads are address-ascending and share cachelines. Unneeded
// lanes (96%) retire before touching W. Each surviving thread copies its
// column (stride D_DIM reads) into a contiguous 512 B row of the staging
// buffer (compiler merges the stores into dwordx4).
__global__ __launch_bounds__(256) void k_gather(const float* __restrict__ W1,
                                                const float* __restrict__ W2,
                                                const int*   __restrict__ inv1,
                                                const int*   __restrict__ inv2,
                                                float* __restrict__ p1,
                                                float* __restrict__ p2)
{
    const float* __restrict__ W   = blockIdx.y ? W2   : W1;
    const int*   __restrict__ inv = blockIdx.y ? inv2 : inv1;
    float*       __restrict__ p   = blockIdx.y ? p2   : p1;

    const int i = blockIdx.x * 256 + threadIdx.x;
    if (i >= D_DIM) return;
    const int j = inv[i];
    if (j == NOREP) return;

    const float* __restrict__ src = W + i;
    float*       __restrict__ dst = p + j * W_DIM;
    #pragma unroll 8
    for (int w = 0; w < W_DIM; ++w)
        dst[w] = src[w * D_DIM];
}

// K4: coalesced dot + sigmoid. Arithmetic is bit-identical to the previous
// monolithic kernel: same values (via representative indirection), same
// bias-add order, same wave-64 butterfly reduction.
__global__ __launch_bounds__(256) void k_dot(const int* __restrict__ idx1,
                                             const int* __restrict__ idx2,
                                             const int* __restrict__ inv1,
                                             const int* __restrict__ inv2,
                                             const float* __restrict__ p1,
                                             const float* __restrict__ p2,
                                             const float* __restrict__ b1,
                                             const float* __restrict__ b2,
                                             float* __restrict__ out)
{
    const int gtid = blockIdx.x * blockDim.x + threadIdx.x;
    const int wave = gtid >> 6;        // batch element
    const int lane = gtid & 63;
    if (wave >= BATCH) return;

    const int r1 = inv1[idx1[wave]];   // representative rows (always valid)
    const int r2 = inv2[idx2[wave]];

    const float* __restrict__ P1 = p1 + r1 * W_DIM;
    const float* __restrict__ P2 = p2 + r2 * W_DIM;

    const int w0 = lane;
    const int w1 = lane + 64;

    const float a0 = P1[w0];
    const float a1 = P1[w1];
    const float c0 = P2[w0];
    const float c1 = P2[w1];

    const float x0 = a0 + b1[w0];
    const float x1 = a1 + b1[w1];
    const float y0 = c0 + b2[w0];
    const float y1 = c1 + b2[w1];

    float v = x0 * y0 + x1 * y1;

    #pragma unroll
    for (int off = 32; off > 0; off >>= 1)
        v += __shfl_down(v, off, 64);

    if (lane == 0) {
        const float s = 1.0f / (1.0f + expf(-v));
        out[wave * 2 + 0] = 1.0f - s;
        out[wave * 2 + 1] = s;
    }
}

extern "C" void kernel_launch(void* const* d_in, const int* in_sizes, int n_in,
                              void* d_out, int out_size, void* d_ws, size_t ws_size,
                              hipStream_t stream)
{
    const int*   idx1 = (const int*)  d_in[0];
    const int*   idx2 = (const int*)  d_in[1];
    const float* W1   = (const float*)d_in[2];
    const float* b1   = (const float*)d_in[3];
    const float* W2   = (const float*)d_in[4];
    const float* b2   = (const float*)d_in[5];
    float* out = (float*)d_out;

    char* ws = (char*)d_ws;
    int*   inv1 = (int*)  (ws + 0);
    int*   inv2 = (int*)  (ws + 400000);
    float* p1   = (float*)(ws + 800000);
    float* p2   = (float*)(ws + 2897152);

    // K1: init inverse maps (contiguous inv1+inv2 region).
    {
        const int n_int4 = (2 * D_DIM) / 4;               // 50000
        const int blocks = (n_int4 + 255) / 256;          // 196
        k_init<<<blocks, 256, 0, stream>>>(inv1);
    }
    // K2: scatter representatives.
    {
        const int blocks = (BATCH + 255) / 256;           // 16
        k_scatter<<<blocks, 256, 0, stream>>>(idx1, idx2, inv1, inv2);
    }
    // K3: inverted gather, both matrices via grid.y.
    {
        dim3 grid((D_DIM + 255) / 256, 2);                // (391, 2)
        k_gather<<<grid, 256, 0, stream>>>(W1, W2, inv1, inv2, p1, p2);
    }
    // K4: dot + sigmoid.
    {
        const int blocks = (BATCH * 64) / 256;            // 1024
        k_dot<<<blocks, 256, 0, stream>>>(idx1, idx2, inv1, inv2,
                                          p1, p2, b1, b2, out);
    }
}

// Round 3
// 125.316 us; speedup vs baseline: 1.0826x; 1.0826x over previous
//
#include <hip/hip_runtime.h>
#include <math.h>

#define D_DIM 100000
#define W_DIM 128
#define BATCH 4096

// One wave (64 lanes) per batch element. Lane l handles dims w=l and w=l+64.
// Structure rationale (round-1 post-mortem): the 4-dispatch dedup pipeline
// saved ~33% of scattered-line traffic but cost 3 dispatch overheads
// (~10.5 us) -> net regression. Single dispatch + max per-wave MLP is the
// best structure; the scattered gather itself is DRAM-random-fetch bound.
__global__ __launch_bounds__(256) void sgns_kernel(
    const int* __restrict__ idx1,
    const int* __restrict__ idx2,
    const float* __restrict__ W1,
    const float* __restrict__ b1,
    const float* __restrict__ W2,
    const float* __restrict__ b2,
    float* __restrict__ out)
{
    const int lane = threadIdx.x & 63;
    const int wave = (blockIdx.x << 2) | (threadIdx.x >> 6);  // grid exact: no bounds check

    // wave is uniform across the 64 lanes; readfirstlane moves it to an SGPR
    // so the idx loads become scalar loads (s_load) -> frees vector-memory
    // slots and shortens the dependent head of the load chain.
    const int wv = __builtin_amdgcn_readfirstlane(wave);
    const int i1 = idx1[wv];
    const int i2 = idx2[wv];

    const int w0 = lane;
    const int w1 = lane + 64;

    // 4 independent scattered loads, issued back-to-back (each on its own
    // cacheline; 400 KB column stride -> no coalescing possible in this
    // layout). These dominate: ~1M distinct lines across the grid,
    // DRAM random-fetch bound.
    const float a0 = W1[w0 * D_DIM + i1];
    const float a1 = W1[w1 * D_DIM + i1];
    const float c0 = W2[w0 * D_DIM + i2];
    const float c1 = W2[w1 * D_DIM + i2];

    // Bias vectors are tiny (128 floats) -> L1/L2 resident.
    const float p0 = a0 + b1[w0];
    const float p1 = a1 + b1[w1];
    const float q0 = c0 + b2[w0];
    const float q1 = c1 + b2[w1];

    float v = p0 * q0 + p1 * q1;

    // Wave-64 butterfly reduction (compiler lowers small offsets to DPP).
    #pragma unroll
    for (int off = 32; off > 0; off >>= 1)
        v += __shfl_down(v, off, 64);

    if (lane == 0) {
        const float s = 1.0f / (1.0f + expf(-v));
        // Single 8 B store instead of two 4 B stores.
        reinterpret_cast<float2*>(out)[wave] = make_float2(1.0f - s, s);
    }
}

extern "C" void kernel_launch(void* const* d_in, const int* in_sizes, int n_in,
                              void* d_out, int out_size, void* d_ws, size_t ws_size,
                              hipStream_t stream)
{
    const int*   idx1 = (const int*)  d_in[0];
    const int*   idx2 = (const int*)  d_in[1];
    const float* W1   = (const float*)d_in[2];
    const float* b1   = (const float*)d_in[3];
    const float* W2   = (const float*)d_in[4];
    const float* b2   = (const float*)d_in[5];
    float* out = (float*)d_out;

    const int threads = 256;                       // 4 waves/block
    const int blocks  = (BATCH * 64) / threads;    // 1024 blocks, 4/CU, all resident
    sgns_kernel<<<blocks, threads, 0, stream>>>(idx1, idx2, W1, b1, W2, b2, out);
}